// Round 5
// baseline (508.523 us; speedup 1.0000x reference)
//
#include <hip/hip_runtime.h>
#include <math.h>

// Problem constants
#define B_    64
#define MAXT  511
#define TP1   512
#define S_    1024
#define H_    4096
#define M_TOTAL (B_*TP1)   // 32768 rows
#define NITER (S_/32)      // 32 K-iterations of BK=32

typedef __attribute__((ext_vector_type(8))) short  short8;   // 8 bf16 (MFMA A/B frag)
typedef __attribute__((ext_vector_type(4))) float  float4v;  // MFMA C/D frag

// ---- workspace layout (bytes) ----
#define ZBUF_BYTES ((size_t)M_TOTAL*4*sizeof(float))   // 524288
#define SBF_OFF    0x81000                             // 528384 >= ZBUF_BYTES
#define SBF_BYTES  ((size_t)M_TOTAL*S_*2)
#define W1T_OFF    (SBF_OFF + SBF_BYTES)

static __device__ __forceinline__ unsigned short f2bf(float f) {
    unsigned int u = __float_as_uint(f);
    u = u + 0x7fffu + ((u >> 16) & 1u);   // round-to-nearest-even
    return (unsigned short)(u >> 16);
}

// ---- merged pre-pass (unchanged from 471us baseline) ----
__global__ __launch_bounds__(256) void prep_kernel(const float* __restrict__ s,
                                                   const float* __restrict__ W1,
                                                   const int*   __restrict__ lengths,
                                                   unsigned short* __restrict__ Sb,
                                                   unsigned short* __restrict__ W1T) {
    int bid = blockIdx.x;
    if (bid < 16384) {
        int row = 2 * bid + (threadIdx.x >> 7);
        int b = row >> 9, t = row & 511;
        if (t >= lengths[b]) return;
        size_t idx = (size_t)row * S_ + (threadIdx.x & 127) * 8;
        float4v f0 = __builtin_nontemporal_load((const float4v*)(s + idx));
        float4v f1 = __builtin_nontemporal_load((const float4v*)(s + idx + 4));
        short8 o;
        o[0] = (short)f2bf(f0[0]); o[1] = (short)f2bf(f0[1]);
        o[2] = (short)f2bf(f0[2]); o[3] = (short)f2bf(f0[3]);
        o[4] = (short)f2bf(f1[0]); o[5] = (short)f2bf(f1[1]);
        o[6] = (short)f2bf(f1[2]); o[7] = (short)f2bf(f1[3]);
        *(short8*)(Sb + idx) = o;
    } else {
        __shared__ float tile[32][33];
        int tb = bid - 16384;
        int h0 = (tb & 127) * 32;
        int k0 = (tb >> 7) * 32;
        int tx = threadIdx.x & 31, ty = threadIdx.x >> 5;
        for (int r = ty; r < 32; r += 8)
            tile[r][tx] = __builtin_nontemporal_load(&W1[(size_t)(k0 + r) * H_ + h0 + tx]);
        __syncthreads();
        for (int r = ty; r < 32; r += 8)
            W1T[(size_t)(h0 + r) * S_ + k0 + tx] = f2bf(tile[tx][r]);
    }
}

// ---- main fused GEMM: 128^2 / BK=32 + gload_lds + 3-buffer counted vmcnt ----
// Round-4 post-mortem: gload_lds with __syncthreads (vmcnt(0) drain every
// K-iter) = 305us / MfmaUtil 26; the 287us reg-staged baseline was faster
// BECAUSE its loads stayed in flight across barriers. This round keeps
// gload_lds (VGPR=60, no reg round-trip) and restores in-flight-across-
// barrier staging with a 3-buffer rotation + counted vmcnt (T3/T4 primitive,
// sync-correctness proven by rounds 2-4 on this harness):
//   iter j: issue STAGE(j+2) -> buf[(j+2)%3]   (4 gload16/wave)
//           ds_read buf[j%3] + 16 MFMA
//           wait vmcnt(4)  -> retires STAGE(j+1), issued at top of iter j-1
//                             (~2 loop bodies of latency cover); NEVER 0
//           s_barrier (raw; no lgkm/vm drain -- ds_reads already retired via
//           MFMA register deps before each wave arrives)
//   tail:   vmcnt(0) once at j==NITER-2.
// WAR: buf[(j+2)%3] last read at iter j-1; writer issues only after the
// end-of-(j-1) barrier, and every wave passed that barrier with reads done.
// LDS 3x(8+8)KB = 48KB -> 3 blocks/CU.
typedef __attribute__((address_space(1))) unsigned int gu32;
typedef __attribute__((address_space(3))) unsigned int lu32;
static __device__ __forceinline__ void gload16(const void* g, void* l) {
    __builtin_amdgcn_global_load_lds((gu32*)g, (lu32*)l, 16, 0, 0);
}

__global__ __launch_bounds__(256, 3) void gemm_fused_kernel(
        const unsigned short* __restrict__ Sb,    // M x S bf16
        const unsigned short* __restrict__ W1T,   // H x S bf16
        const float* __restrict__ b1,             // H
        const float* __restrict__ W2,             // H x 32 fp32 (cols 0..3 used)
        const int*   __restrict__ lengths,        // B
        float*       __restrict__ zbuf)           // M x 4
{
    int id   = blockIdx.x;
    int xcd  = id & 7;
    int slot = id >> 3;                  // 0..1023
    int ntile = xcd * 4 + (slot & 3);    // 0..31 (inner: A-panel L2 reuse)
    int mtile = slot >> 2;               // 0..255

    int b  = mtile >> 2;
    int t0 = (mtile & 3) * 128;
    if (lengths[b] <= t0) return;        // whole 128-row tile masked out (uniform)

    int m0 = mtile * 128;
    int n0 = ntile * 128;

    __shared__ unsigned short smemA[3 * 128 * 32];   // 3 x 8 KB
    __shared__ unsigned short smemB[3 * 128 * 32];   // 3 x 8 KB

    int tid  = threadIdx.x;
    int wid  = tid >> 6;
    int lane = tid & 63;
    int lane15 = lane & 15;
    int quad   = lane >> 4;
    int wave_m = (wid >> 1) * 64;
    int wave_n = (wid & 1) * 64;

    // staging chunk map: chunk c -> row m=c>>2, slot cp=c&3, global k-chunk
    // q = cp ^ ((m>>1)&3)  (XOR swizzle, involution; LDS stays linear)
    int cA0 = tid, cA1 = tid + 256;
    int mA0 = cA0 >> 2, q0 = (cA0 & 3) ^ ((mA0 >> 1) & 3);
    int mA1 = cA1 >> 2, q1 = (cA1 & 3) ^ ((mA1 >> 1) & 3);

    const char* gA0 = (const char*)Sb  + (size_t)(m0 + mA0) * (S_*2) + q0 * 16;
    const char* gA1 = (const char*)Sb  + (size_t)(m0 + mA1) * (S_*2) + q1 * 16;
    const char* gB0 = (const char*)W1T + (size_t)(n0 + mA0) * (S_*2) + q0 * 16;
    const char* gB1 = (const char*)W1T + (size_t)(n0 + mA1) * (S_*2) + q1 * 16;
    char* lwA0 = (char*)smemA + cA0 * 16;   // buf0 write addrs; buf k = +k*8192
    char* lwA1 = (char*)smemA + cA1 * 16;
    char* lwB0 = (char*)smemB + cA0 * 16;
    char* lwB1 = (char*)smemB + cA1 * 16;

    // fragment read offsets within a buffer (in shorts) -- measured 0 conflicts
    int aOff[4], bOff[4];
#pragma unroll
    for (int s = 0; s < 4; s++) {
        int ml = wave_m + s * 16 + lane15;
        aOff[s] = ml * 32 + (quad ^ ((ml >> 1) & 3)) * 8;
        int nl = wave_n + s * 16 + lane15;
        bOff[s] = nl * 32 + (quad ^ ((nl >> 1) & 3)) * 8;
    }

#define STAGE(bufsel, jj) do { \
    int off_ = (jj) * 64; int lb_ = (bufsel) * 8192; \
    gload16(gA0 + off_, lwA0 + lb_); \
    gload16(gA1 + off_, lwA1 + lb_); \
    gload16(gB0 + off_, lwB0 + lb_); \
    gload16(gB1 + off_, lwB1 + lb_); \
} while (0)

    float4v acc[4][4] = {};

    // prologue: stage tiles 0,1 (8 loads/wave); retire tile 0 only (vmcnt 4)
    STAGE(0, 0);
    STAGE(1, 1);
    asm volatile("s_waitcnt vmcnt(4)" ::: "memory");
    __builtin_amdgcn_sched_barrier(0);
    __builtin_amdgcn_s_barrier();
    __builtin_amdgcn_sched_barrier(0);

    int rb = 0;                          // read-buffer index = j%3 (rotated)
    for (int j = 0; j < NITER; j++) {
        if (j + 2 < NITER) {
            int wb = rb + 2; if (wb >= 3) wb -= 3;
            STAGE(wb, j + 2);
        }
        const unsigned short* aP = smemA + rb * 4096;
        const unsigned short* bP = smemB + rb * 4096;
        short8 af[4], bf[4];
#pragma unroll
        for (int s = 0; s < 4; s++) {
            af[s] = *(const short8*)(aP + aOff[s]);
            bf[s] = *(const short8*)(bP + bOff[s]);
        }
#pragma unroll
        for (int i = 0; i < 4; i++)
#pragma unroll
            for (int jj = 0; jj < 4; jj++)
                acc[i][jj] = __builtin_amdgcn_mfma_f32_16x16x32_bf16(af[i], bf[jj], acc[i][jj], 0, 0, 0);
        // counted wait: retire STAGE(j+1) (issued top of iter j-1); never 0 mid-loop
        if (j < NITER - 2)       { asm volatile("s_waitcnt vmcnt(4)" ::: "memory"); }
        else if (j == NITER - 2) { asm volatile("s_waitcnt vmcnt(0)" ::: "memory"); }
        __builtin_amdgcn_sched_barrier(0);
        __builtin_amdgcn_s_barrier();
        __builtin_amdgcn_sched_barrier(0);
        rb = rb + 1; if (rb >= 3) rb = 0;
    }
#undef STAGE

    // ---- fused epilogue: relu(h) @ W2[:,0:4], shuffle-reduce, atomicAdd ----
    float4v w2r[4];
    float   b1v[4];
#pragma unroll
    for (int ns = 0; ns < 4; ns++) {
        int n_g = n0 + wave_n + ns * 16 + lane15;
        w2r[ns] = *(const float4v*)(W2 + (size_t)n_g * 32);
        b1v[ns] = b1[n_g];
    }
#pragma unroll
    for (int ms = 0; ms < 4; ms++) {
        float p[4][4];
#pragma unroll
        for (int r = 0; r < 4; r++)
#pragma unroll
            for (int c = 0; c < 4; c++) p[r][c] = 0.f;
#pragma unroll
        for (int ns = 0; ns < 4; ns++) {
            float4v av = acc[ms][ns];
#pragma unroll
            for (int r = 0; r < 4; r++) {
                float h = av[r] + b1v[ns];
                h = h > 0.f ? h : 0.f;
                p[r][0] += h * w2r[ns][0];
                p[r][1] += h * w2r[ns][1];
                p[r][2] += h * w2r[ns][2];
                p[r][3] += h * w2r[ns][3];
            }
        }
#pragma unroll
        for (int off = 1; off < 16; off <<= 1)
#pragma unroll
            for (int r = 0; r < 4; r++)
#pragma unroll
                for (int c = 0; c < 4; c++)
                    p[r][c] += __shfl_xor(p[r][c], off);
        if (lane15 < 4) {
            int c = lane15;
#pragma unroll
            for (int r = 0; r < 4; r++) {
                int mg = m0 + wave_m + ms * 16 + quad * 4 + r;
                atomicAdd(&zbuf[(size_t)mg * 4 + c], p[r][c]);
            }
        }
    }
}

// ---- log-softmax gather + masked sum (unchanged) ----
__global__ __launch_bounds__(128) void reduce_logp_kernel(
        const float* __restrict__ zbuf,
        const int*   __restrict__ actions,
        const int*   __restrict__ lengths,
        const float* __restrict__ b2,
        float*       __restrict__ out)
{
    int b = blockIdx.x;
    int t = blockIdx.y * 128 + threadIdx.x;
    int len = lengths[b];
    float local = 0.f;
    if (t < MAXT && t < len) {
        int row = b * TP1 + t;
        float4v z = *(const float4v*)(zbuf + (size_t)row * 4);
        float z0 = z[0] + b2[0], z1 = z[1] + b2[1], z2 = z[2] + b2[2], z3 = z[3] + b2[3];
        float mx = fmaxf(fmaxf(z0, z1), fmaxf(z2, z3));
        float se = expf(z0 - mx) + expf(z1 - mx) + expf(z2 - mx) + expf(z3 - mx);
        int a = actions[b * MAXT + t];
        float za = (a == 0) ? z0 : (a == 1) ? z1 : (a == 2) ? z2 : z3;
        local = (za - mx) - logf(se);
    }
#pragma unroll
    for (int off = 32; off > 0; off >>= 1) local += __shfl_xor(local, off);
    __shared__ float wsum[2];
    if ((threadIdx.x & 63) == 0) wsum[threadIdx.x >> 6] = local;
    __syncthreads();
    if (threadIdx.x == 0) atomicAdd(out, -(wsum[0] + wsum[1]));   // out = -sum(logp)
}

extern "C" void kernel_launch(void* const* d_in, const int* in_sizes, int n_in,
                              void* d_out, int out_size, void* d_ws, size_t ws_size,
                              hipStream_t stream) {
    const float* s       = (const float*)d_in[0];  // (64,512,1024) fp32
    const int*   actions = (const int*)  d_in[1];  // (64,511)
    const int*   lengths = (const int*)  d_in[2];  // (64,)
    const float* W1      = (const float*)d_in[3];  // (1024,4096)
    const float* b1      = (const float*)d_in[4];  // (4096,)
    const float* W2      = (const float*)d_in[5];  // (4096,32)
    const float* b2      = (const float*)d_in[6];  // (32,)

    char* ws = (char*)d_ws;
    float*          zbuf = (float*)ws;             // [0, 512KB)
    unsigned short* Sb   = (unsigned short*)(ws + SBF_OFF);
    unsigned short* W1T  = (unsigned short*)(ws + W1T_OFF);

    hipMemsetAsync(ws, 0, ZBUF_BYTES, stream);
    hipMemsetAsync(d_out, 0, sizeof(float), stream);

    // merged pre-pass: s->bf16 (live rows, nt loads) + W1->W1T bf16
    prep_kernel<<<dim3(16384 + 4096), 256, 0, stream>>>(s, W1, lengths, Sb, W1T);
    // fused GEMM + relu + W2[:,0:4] projection (XCD-swizzled 1D grid)
    gemm_fused_kernel<<<dim3(8192), 256, 0, stream>>>(Sb, W1T, b1, W2, lengths, zbuf);
    // log-softmax gather + masked sum -> d_out
    reduce_logp_kernel<<<dim3(B_, 4), 128, 0, stream>>>(zbuf, actions, lengths, b2, (float*)d_out);
}

// Round 6
// 426.038 us; speedup vs baseline: 1.1936x; 1.1936x over previous
//
#include <hip/hip_runtime.h>
#include <math.h>

// Problem constants
#define B_    64
#define MAXT  511
#define TP1   512
#define S_    1024
#define H_    4096
#define M_TOTAL (B_*TP1)   // 32768 rows
#define NITER (S_/32)      // 32 K-iterations

typedef __attribute__((ext_vector_type(8))) short  short8;   // 8 bf16 = 4 VGPRs (MFMA A/B frag)
typedef __attribute__((ext_vector_type(4))) float  float4v;  // MFMA C/D frag

// ---- workspace layout (bytes) ----
// zbuf [0, 512KB) ; offs [512KB, +260B) ; Sb at SBF_OFF ; W1T after
#define ZBUF_BYTES ((size_t)M_TOTAL*4*sizeof(float))   // 524288
#define OFFS_OFF   0x80000                             // 524288 (65 ints)
#define SBF_OFF    0x81000                             // 528384
#define SBF_BYTES  ((size_t)M_TOTAL*S_*2)
#define W1T_OFF    (SBF_OFF + SBF_BYTES)

static __device__ __forceinline__ unsigned short f2bf(float f) {
    unsigned int u = __float_as_uint(f);
    u = u + 0x7fffu + ((u >> 16) & 1u);   // round-to-nearest-even
    return (unsigned short)(u >> 16);
}

// ---- row-compaction offsets: exclusive prefix sum of lengths (1 wave) ----
// offs[b] = sum(lengths[<b]); offs[64] = M_live. Rounds 0-5 computed 160
// live 128-tiles (tile-granular mask, E=0.625); compaction computes 128
// (E[sum len]=16320 rows): -20% GEMM work, schedule untouched.
__global__ __launch_bounds__(64) void offsets_kernel(const int* __restrict__ lengths,
                                                     int* __restrict__ offs) {
    int lane = threadIdx.x;
    int v = lengths[lane];
    int x = v;
#pragma unroll
    for (int d = 1; d < 64; d <<= 1) {
        int y = __shfl_up(x, d);
        if (lane >= d) x += y;
    }
    offs[lane] = x - v;           // exclusive
    if (lane == 63) offs[64] = x; // total live rows
}

// ---- merged pre-pass: s -> COMPACTED bf16 rows + W1 -> W1T bf16 ----
__global__ __launch_bounds__(256) void prep_kernel(const float* __restrict__ s,
                                                   const float* __restrict__ W1,
                                                   const int*   __restrict__ lengths,
                                                   const int*   __restrict__ offs,
                                                   unsigned short* __restrict__ Sb,
                                                   unsigned short* __restrict__ W1T) {
    int bid = blockIdx.x;
    if (bid < 16384) {
        int row = 2 * bid + (threadIdx.x >> 7);          // global (b,t) row
        int b = row >> 9, t = row & 511;
        if (t >= lengths[b]) return;                     // dead row: not staged
        int crow = offs[b] + t;                          // compact destination
        size_t src = (size_t)row  * S_ + (threadIdx.x & 127) * 8;
        size_t dst = (size_t)crow * S_ + (threadIdx.x & 127) * 8;
        float4v f0 = __builtin_nontemporal_load((const float4v*)(s + src));
        float4v f1 = __builtin_nontemporal_load((const float4v*)(s + src + 4));
        short8 o;
        o[0] = (short)f2bf(f0[0]); o[1] = (short)f2bf(f0[1]);
        o[2] = (short)f2bf(f0[2]); o[3] = (short)f2bf(f0[3]);
        o[4] = (short)f2bf(f1[0]); o[5] = (short)f2bf(f1[1]);
        o[6] = (short)f2bf(f1[2]); o[7] = (short)f2bf(f1[3]);
        *(short8*)(Sb + dst) = o;
    } else {
        __shared__ float tile[32][33];
        int tb = bid - 16384;
        int h0 = (tb & 127) * 32;                        // H dim
        int k0 = (tb >> 7) * 32;                         // S dim
        int tx = threadIdx.x & 31, ty = threadIdx.x >> 5; // 32 x 8
        for (int r = ty; r < 32; r += 8)
            tile[r][tx] = __builtin_nontemporal_load(&W1[(size_t)(k0 + r) * H_ + h0 + tx]);
        __syncthreads();
        for (int r = ty; r < 32; r += 8)
            W1T[(size_t)(h0 + r) * S_ + k0 + tx] = f2bf(tile[tx][r]);
    }
}

// ---- main fused GEMM: EXACT 287us structure (reg-staged, distance-2) ----
// Rounds 2-5 proved every schedule variant (8-phase 256^2 x2, gload_lds
// 2-phase, gload_lds 3-buf counted-vmcnt) regresses vs this body: 445/410/
// 305/342 vs 287. Body byte-identical to round-0; only the tile-skip changed
// to the compacted predicate (m0 >= M_live). Tail-tile rows >= M_live read
// poisoned Sb but GEMM rows are independent -> garbage lands only in zbuf
// rows >= M_live, which reduce never reads.
__global__ __launch_bounds__(256, 3) void gemm_fused_kernel(
        const unsigned short* __restrict__ Sb,    // M_live x S bf16 (compact)
        const unsigned short* __restrict__ W1T,   // H x S bf16
        const float* __restrict__ b1,             // H
        const float* __restrict__ W2,             // H x 32 fp32 (cols 0..3 used)
        const int*   __restrict__ offs,           // [65]; offs[64] = M_live
        float*       __restrict__ zbuf)           // M x 4 (compact rows)
{
    int id   = blockIdx.x;
    int xcd  = id & 7;
    int slot = id >> 3;                  // 0..1023
    int ntile = xcd * 4 + (slot & 3);    // 0..31
    int mtile = slot >> 2;               // 0..255

    int m0 = mtile * 128;
    if (m0 >= offs[64]) return;          // beyond compacted rows (uniform)

    int n0 = ntile * 128;

    __shared__ unsigned short smemA[2 * 128 * 32];   // 2 x 8 KB
    __shared__ unsigned short smemB[2 * 128 * 32];   // 2 x 8 KB

    int tid  = threadIdx.x;
    int wid  = tid >> 6;
    int lane = tid & 63;
    int lane15 = lane & 15;
    int quad   = lane >> 4;
    int wave_m = (wid >> 1) * 64;
    int wave_n = (wid & 1) * 64;

    // staging chunk map: chunk c -> row m=c>>2, slot cp=c&3, global k-chunk
    // q = cp ^ ((m>>1)&3)  (XOR swizzle -> 2-way-free LDS access)
    int cA0 = tid, cA1 = tid + 256;
    int mA0 = cA0 >> 2, cp0 = cA0 & 3, q0 = cp0 ^ ((mA0 >> 1) & 3);
    int mA1 = cA1 >> 2, cp1 = cA1 & 3, q1 = cp1 ^ ((mA1 >> 1) & 3);

    const char* gA0 = (const char*)Sb  + (size_t)(m0 + mA0) * (S_*2) + q0 * 16;
    const char* gA1 = (const char*)Sb  + (size_t)(m0 + mA1) * (S_*2) + q1 * 16;
    const char* gB0 = (const char*)W1T + (size_t)(n0 + mA0) * (S_*2) + q0 * 16;
    const char* gB1 = (const char*)W1T + (size_t)(n0 + mA1) * (S_*2) + q1 * 16;
    char* lwA0 = (char*)smemA + cA0 * 16;   // buf0 write addrs; buf1 = +8192
    char* lwA1 = (char*)smemA + cA1 * 16;
    char* lwB0 = (char*)smemB + cA0 * 16;
    char* lwB1 = (char*)smemB + cA1 * 16;

    // fragment read offsets within a buffer (in shorts)
    int aOff[4], bOff[4];
#pragma unroll
    for (int s = 0; s < 4; s++) {
        int ml = wave_m + s * 16 + lane15;
        aOff[s] = ml * 32 + (quad ^ ((ml >> 1) & 3)) * 8;
        int nl = wave_n + s * 16 + lane15;
        bOff[s] = nl * 32 + (quad ^ ((nl >> 1) & 3)) * 8;
    }

    float4v acc[4][4] = {};
    short8 sA0[3], sA1[3], sB0[3], sB1[3];   // 3 register sets -> distance-2 pipeline

    // prologue: issue loads for iters 0,1,2 (constant offsets, monotone vmcnt order)
#pragma unroll
    for (int p = 0; p < 3; p++) {
        sA0[p] = *(const short8*)(gA0 + p * 64);
        sA1[p] = *(const short8*)(gA1 + p * 64);
        sB0[p] = *(const short8*)(gB0 + p * 64);
        sB1[p] = *(const short8*)(gB1 + p * 64);
    }
    // stage iter 0 into buf0 (compiler waits vmcnt only for set 0)
    *(short8*)lwA0 = sA0[0]; *(short8*)lwA1 = sA1[0];
    *(short8*)lwB0 = sB0[0]; *(short8*)lwB1 = sB1[0];

#pragma unroll
    for (int j = 0; j < NITER; j++) {
        __syncthreads();   // buf[j&1] staged (lgkmcnt only -- no global drain)
        // refill the set just consumed: data for iter j+3, in flight for 2 sub-iters
        if (j + 3 < NITER) {
            sA0[j % 3] = *(const short8*)(gA0 + (j + 3) * 64);
            sA1[j % 3] = *(const short8*)(gA1 + (j + 3) * 64);
            sB0[j % 3] = *(const short8*)(gB0 + (j + 3) * 64);
            sB1[j % 3] = *(const short8*)(gB1 + (j + 3) * 64);
        }
        // stage iter j+1 into the other buffer
        if (j + 1 < NITER) {
            int nb = ((j + 1) & 1) * 8192;
            *(short8*)(lwA0 + nb) = sA0[(j + 1) % 3];
            *(short8*)(lwA1 + nb) = sA1[(j + 1) % 3];
            *(short8*)(lwB0 + nb) = sB0[(j + 1) % 3];
            *(short8*)(lwB1 + nb) = sB1[(j + 1) % 3];
        }
        // compute iter j from buf[j&1]
        const unsigned short* aP = smemA + (j & 1) * 4096;
        const unsigned short* bP = smemB + (j & 1) * 4096;
        short8 af[4], bf[4];
#pragma unroll
        for (int s = 0; s < 4; s++) {
            af[s] = *(const short8*)(aP + aOff[s]);
            bf[s] = *(const short8*)(bP + bOff[s]);
        }
#pragma unroll
        for (int i = 0; i < 4; i++)
#pragma unroll
            for (int jj = 0; jj < 4; jj++)
                acc[i][jj] = __builtin_amdgcn_mfma_f32_16x16x32_bf16(af[i], bf[jj], acc[i][jj], 0, 0, 0);
    }

    // ---- fused epilogue: relu(h) @ W2[:,0:4], shuffle-reduce, atomicAdd ----
    float4v w2r[4];
    float   b1v[4];
#pragma unroll
    for (int ns = 0; ns < 4; ns++) {
        int n_g = n0 + wave_n + ns * 16 + lane15;
        w2r[ns] = *(const float4v*)(W2 + (size_t)n_g * 32);
        b1v[ns] = b1[n_g];
    }
#pragma unroll
    for (int ms = 0; ms < 4; ms++) {
        float p[4][4];
#pragma unroll
        for (int r = 0; r < 4; r++)
#pragma unroll
            for (int c = 0; c < 4; c++) p[r][c] = 0.f;
#pragma unroll
        for (int ns = 0; ns < 4; ns++) {
            float4v av = acc[ms][ns];
#pragma unroll
            for (int r = 0; r < 4; r++) {
                float h = av[r] + b1v[ns];
                h = h > 0.f ? h : 0.f;
                p[r][0] += h * w2r[ns][0];
                p[r][1] += h * w2r[ns][1];
                p[r][2] += h * w2r[ns][2];
                p[r][3] += h * w2r[ns][3];
            }
        }
#pragma unroll
        for (int off = 1; off < 16; off <<= 1)
#pragma unroll
            for (int r = 0; r < 4; r++)
#pragma unroll
                for (int c = 0; c < 4; c++)
                    p[r][c] += __shfl_xor(p[r][c], off);
        if (lane15 < 4) {
            int c = lane15;
#pragma unroll
            for (int r = 0; r < 4; r++) {
                int mg = m0 + wave_m + ms * 16 + quad * 4 + r;
                atomicAdd(&zbuf[(size_t)mg * 4 + c], p[r][c]);
            }
        }
    }
}

// ---- log-softmax gather + masked sum (compact row indexing) ----
__global__ __launch_bounds__(128) void reduce_logp_kernel(
        const float* __restrict__ zbuf,
        const int*   __restrict__ actions,
        const int*   __restrict__ lengths,
        const int*   __restrict__ offs,
        const float* __restrict__ b2,
        float*       __restrict__ out)
{
    int b = blockIdx.x;
    int t = blockIdx.y * 128 + threadIdx.x;
    int len = lengths[b];
    float local = 0.f;
    if (t < MAXT && t < len) {
        int row = offs[b] + t;                       // compact row
        float4v z = *(const float4v*)(zbuf + (size_t)row * 4);
        float z0 = z[0] + b2[0], z1 = z[1] + b2[1], z2 = z[2] + b2[2], z3 = z[3] + b2[3];
        float mx = fmaxf(fmaxf(z0, z1), fmaxf(z2, z3));
        float se = expf(z0 - mx) + expf(z1 - mx) + expf(z2 - mx) + expf(z3 - mx);
        int a = actions[b * MAXT + t];
        float za = (a == 0) ? z0 : (a == 1) ? z1 : (a == 2) ? z2 : z3;
        local = (za - mx) - logf(se);
    }
#pragma unroll
    for (int off = 32; off > 0; off >>= 1) local += __shfl_xor(local, off);
    __shared__ float wsum[2];
    if ((threadIdx.x & 63) == 0) wsum[threadIdx.x >> 6] = local;
    __syncthreads();
    if (threadIdx.x == 0) atomicAdd(out, -(wsum[0] + wsum[1]));   // out = -sum(logp)
}

extern "C" void kernel_launch(void* const* d_in, const int* in_sizes, int n_in,
                              void* d_out, int out_size, void* d_ws, size_t ws_size,
                              hipStream_t stream) {
    const float* s       = (const float*)d_in[0];  // (64,512,1024) fp32
    const int*   actions = (const int*)  d_in[1];  // (64,511)
    const int*   lengths = (const int*)  d_in[2];  // (64,)
    const float* W1      = (const float*)d_in[3];  // (1024,4096)
    const float* b1      = (const float*)d_in[4];  // (4096,)
    const float* W2      = (const float*)d_in[5];  // (4096,32)
    const float* b2      = (const float*)d_in[6];  // (32,)

    char* ws = (char*)d_ws;
    float*          zbuf = (float*)ws;             // [0, 512KB)
    int*            offs = (int*)(ws + OFFS_OFF);  // [65]
    unsigned short* Sb   = (unsigned short*)(ws + SBF_OFF);
    unsigned short* W1T  = (unsigned short*)(ws + W1T_OFF);

    // zero z-buffer and output accumulator (ws/out poisoned 0xAA before every launch)
    hipMemsetAsync(ws, 0, ZBUF_BYTES, stream);
    hipMemsetAsync(d_out, 0, sizeof(float), stream);

    // row-compaction offsets (1 wave)
    offsets_kernel<<<dim3(1), 64, 0, stream>>>(lengths, offs);
    // merged pre-pass: s->bf16 compacted rows + W1->W1T bf16
    prep_kernel<<<dim3(16384 + 4096), 256, 0, stream>>>(s, W1, lengths, offs, Sb, W1T);
    // fused GEMM + relu + W2[:,0:4] projection (XCD-swizzled 1D grid)
    gemm_fused_kernel<<<dim3(8192), 256, 0, stream>>>(Sb, W1T, b1, W2, offs, zbuf);
    // log-softmax gather + masked sum -> d_out
    reduce_logp_kernel<<<dim3(B_, 4), 128, 0, stream>>>(zbuf, actions, lengths, offs, b2, (float*)d_out);
}